// Round 7
// baseline (149.335 us; speedup 1.0000x reference)
//
#include <hip/hip_runtime.h>
#include <cstddef>

#define TDIM 1024
#define SEQ 8192
#define NROWS 4096

typedef float f32x4 __attribute__((ext_vector_type(4)));

// Kernel 1: one block per table value r (1024 blocks).
// Block-local histogram of his, then masked max + count-weighted exp-sum
// over row r of M. Writes scales[r] = (masked_max, 1/S).
__global__ __launch_bounds__(256) void stats_kernel(
    const int* __restrict__ his, const float* __restrict__ M,
    float2* __restrict__ scales)
{
    __shared__ int lc[TDIM];
    __shared__ float red[8];
    const int tid = threadIdx.x;
    const int r = blockIdx.x;

#pragma unroll
    for (int k = 0; k < 4; ++k) lc[tid + 256 * k] = 0;

    const int4* his4 = (const int4*)his;       // 2048 int4
    int4 h[8];
#pragma unroll
    for (int it = 0; it < 8; ++it) h[it] = his4[it * 256 + tid];

    const float* Mrow = M + (size_t)r * TDIM;
    float m[4];
#pragma unroll
    for (int k = 0; k < 4; ++k) m[k] = Mrow[tid + 256 * k];

    __syncthreads();
#pragma unroll
    for (int it = 0; it < 8; ++it) {
        atomicAdd(&lc[h[it].x], 1);
        atomicAdd(&lc[h[it].y], 1);
        atomicAdd(&lc[h[it].z], 1);
        atomicAdd(&lc[h[it].w], 1);
    }
    __syncthreads();

    int c[4];
#pragma unroll
    for (int k = 0; k < 4; ++k) c[k] = lc[tid + 256 * k];

    float lmax = -3.402823466e38f;
#pragma unroll
    for (int k = 0; k < 4; ++k)
        if (c[k] > 0) lmax = fmaxf(lmax, m[k]);
#pragma unroll
    for (int off = 32; off > 0; off >>= 1)
        lmax = fmaxf(lmax, __shfl_down(lmax, off, 64));
    const int wave = tid >> 6, lane = tid & 63;
    if (lane == 0) red[wave] = lmax;
    __syncthreads();
    const float gmax = fmaxf(fmaxf(red[0], red[1]), fmaxf(red[2], red[3]));

    float lsum = 0.f;
#pragma unroll
    for (int k = 0; k < 4; ++k)
        lsum += (float)c[k] * __expf(m[k] - gmax);
#pragma unroll
    for (int off = 32; off > 0; off >>= 1)
        lsum += __shfl_down(lsum, off, 64);
    if (lane == 0) red[4 + wave] = lsum;
    __syncthreads();
    if (tid == 0) {
        float s = red[4] + red[5] + red[6] + red[7];
        scales[r] = make_float2(gmax, 1.0f / s);
    }
}

// Kernel 2: IDENTICAL to Round 6's out_kernel, plus a DIAGNOSTIC second
// pass: re-gather from the still-valid LDS prob tables and re-store the
// same values with non-temporal stores. Output is unchanged (same bits
// written twice); the marginal duration isolates the gather+store cost.
__global__ __launch_bounds__(256) void out_kernel(
    const int* __restrict__ his, const int* __restrict__ cur,
    const float* __restrict__ M, const float2* __restrict__ scales,
    float* __restrict__ out)
{
    __shared__ float prob[2][TDIM];
    const int tid = threadIdx.x;
    const int row0 = blockIdx.x * 2;
    const int r0 = cur[row0];
    const int r1 = cur[row0 + 1];
    const float2 s0 = scales[r0];
    const float2 s1 = scales[r1];
    const float* M0 = M + (size_t)r0 * TDIM;
    const float* M1 = M + (size_t)r1 * TDIM;

    const int4* his4 = (const int4*)his;       // 2048 int4
    int4 h[8];
#pragma unroll
    for (int it = 0; it < 8; ++it) h[it] = his4[it * 256 + tid];

#pragma unroll
    for (int k = 0; k < 4; ++k) {
        int t = tid + 256 * k;
        prob[0][t] = __expf(M0[t] - s0.x) * s0.y;
        prob[1][t] = __expf(M1[t] - s1.x) * s1.y;
    }
    __syncthreads();

    // --- pass 1: normal stores (byte-identical to Round 6) ---
    f32x4* o0 = (f32x4*)(out + (size_t)row0 * SEQ);
    f32x4* o1 = (f32x4*)(out + (size_t)(row0 + 1) * SEQ);
#pragma unroll
    for (int it = 0; it < 8; ++it) {
        const int4 hh = h[it];
        f32x4 a, b;
        a.x = prob[0][hh.x];  b.x = prob[1][hh.x];
        a.y = prob[0][hh.y];  b.y = prob[1][hh.y];
        a.z = prob[0][hh.z];  b.z = prob[1][hh.z];
        a.w = prob[0][hh.w];  b.w = prob[1][hh.w];
        o0[it * 256 + tid] = a;
        o1[it * 256 + tid] = b;
    }

    // compiler memory barrier: keeps pass-1 stores live (no DSE) and
    // forces pass-2 to re-read LDS rather than CSE pass-1's loads.
    asm volatile("" ::: "memory");

    // --- pass 2 (diagnostic): same values, non-temporal stores ---
#pragma unroll
    for (int it = 0; it < 8; ++it) {
        const int4 hh = h[it];
        f32x4 a, b;
        a.x = prob[0][hh.x];  b.x = prob[1][hh.x];
        a.y = prob[0][hh.y];  b.y = prob[1][hh.y];
        a.z = prob[0][hh.z];  b.z = prob[1][hh.z];
        a.w = prob[0][hh.w];  b.w = prob[1][hh.w];
        __builtin_nontemporal_store(a, &o0[it * 256 + tid]);
        __builtin_nontemporal_store(b, &o1[it * 256 + tid]);
    }
}

// Fallback: Round-4 fully fused single kernel (no workspace needed).
__global__ __launch_bounds__(256) void fused_kernel(
    const int* __restrict__ his, const int* __restrict__ cur,
    const float* __restrict__ M, float* __restrict__ out)
{
    __shared__ float mrow[TDIM];
    __shared__ float redm[4];
    __shared__ float reds[4];

    const int tid = threadIdx.x;
    const int row = blockIdx.x;
    const int r = cur[row];
    const float* Mrow = M + (size_t)r * TDIM;

    const int4* his4 = (const int4*)his;
    int4 h[8];
#pragma unroll
    for (int it = 0; it < 8; ++it) h[it] = his4[it * 256 + tid];

#pragma unroll
    for (int k = 0; k < 4; ++k) mrow[tid + 256 * k] = Mrow[tid + 256 * k];
    __syncthreads();

    float g[32];
#pragma unroll
    for (int it = 0; it < 8; ++it) {
        g[4 * it + 0] = mrow[h[it].x];
        g[4 * it + 1] = mrow[h[it].y];
        g[4 * it + 2] = mrow[h[it].z];
        g[4 * it + 3] = mrow[h[it].w];
    }

    float mloc = g[0];
#pragma unroll
    for (int j = 1; j < 32; ++j) mloc = fmaxf(mloc, g[j]);
    float e[32];
    float s = 0.f;
#pragma unroll
    for (int j = 0; j < 32; ++j) {
        e[j] = __expf(g[j] - mloc);
        s += e[j];
    }

    float m = mloc;
#pragma unroll
    for (int off = 32; off > 0; off >>= 1) {
        float om = __shfl_xor(m, off, 64);
        float os = __shfl_xor(s, off, 64);
        float nm_ = fmaxf(m, om);
        s = s * __expf(m - nm_) + os * __expf(om - nm_);
        m = nm_;
    }

    const int wave = tid >> 6, lane = tid & 63;
    if (lane == 0) { redm[wave] = m; reds[wave] = s; }
    __syncthreads();
    float M0 = redm[0], S0 = reds[0];
#pragma unroll
    for (int w = 1; w < 4; ++w) {
        float mw = redm[w], sw = reds[w];
        float nm_ = fmaxf(M0, mw);
        S0 = S0 * __expf(M0 - nm_) + sw * __expf(mw - nm_);
        M0 = nm_;
    }

    const float scale = __expf(mloc - M0) / S0;

    f32x4* out4 = (f32x4*)(out + (size_t)row * SEQ);
#pragma unroll
    for (int it = 0; it < 8; ++it) {
        f32x4 o;
        o.x = e[4 * it + 0] * scale;
        o.y = e[4 * it + 1] * scale;
        o.z = e[4 * it + 2] * scale;
        o.w = e[4 * it + 3] * scale;
        out4[it * 256 + tid] = o;
    }
}

extern "C" void kernel_launch(void* const* d_in, const int* in_sizes, int n_in,
                              void* d_out, int out_size, void* d_ws, size_t ws_size,
                              hipStream_t stream) {
    const int*   his = (const int*)d_in[0];    // (8192,) int32 in [0,1024)
    const int*   cur = (const int*)d_in[1];    // (4096,) int32 in [0,1024)
    const float* M   = (const float*)d_in[2];  // (1024,1024) fp32
    float* out = (float*)d_out;                // (4096,8192) fp32

    if (ws_size >= TDIM * sizeof(float2)) {
        float2* scales = (float2*)d_ws;        // 8 KB scratch
        stats_kernel<<<TDIM, 256, 0, stream>>>(his, M, scales);
        out_kernel<<<NROWS / 2, 256, 0, stream>>>(his, cur, M, scales, out);
    } else {
        fused_kernel<<<NROWS, 256, 0, stream>>>(his, cur, M, out);
    }
}

// Round 8
// 144.346 us; speedup vs baseline: 1.0346x; 1.0346x over previous
//
#include <hip/hip_runtime.h>
#include <cstddef>

#define TDIM 1024
#define SEQ 8192
#define NROWS 4096

typedef float f32x4 __attribute__((ext_vector_type(4)));

// Best-of-session (Round 4, 143.54 us): one block per output row, fully
// fused, single dispatch, no workspace. Softmax statistics are computed
// directly on the gathered multiset:
//   max_j M[r][his[j]]  == masked max over present table columns
//   sum_j exp(..)       == histogram-weighted sum (multiplicity implicit)
// Phases: stage Mrow->LDS | gather 32 raw vals/thread | per-thread (m,s) |
// fused butterfly (m,s) merge | cross-wave merge | scale+store from regs.
// 2 barriers, 1 LDS gather, zero LDS atomics.
//
// Session evidence (R7 diagnostic): an ENTIRE extra gather+store pass of
// the 128 MiB output costs only ~4.4 us marginal (stores are LLC-absorbed)
// — the kernel data path is not the bottleneck; the bench window is
// dominated by harness fills (~80 us poison re-fill inside the window).
__global__ __launch_bounds__(256) void fused_kernel(
    const int* __restrict__ his, const int* __restrict__ cur,
    const float* __restrict__ M, float* __restrict__ out)
{
    __shared__ float mrow[TDIM];
    __shared__ float redm[4];
    __shared__ float reds[4];

    const int tid = threadIdx.x;
    const int row = blockIdx.x;
    const int r = cur[row];                    // wave-uniform broadcast load
    const float* Mrow = M + (size_t)r * TDIM;

    // his into registers: int4 x 8 = 32 indices/thread (reused for output)
    const int4* his4 = (const int4*)his;       // 2048 int4
    int4 h[8];
#pragma unroll
    for (int it = 0; it < 8; ++it) h[it] = his4[it * 256 + tid];

    // stage M row into LDS (4 KB, coalesced, L2-resident source)
#pragma unroll
    for (int k = 0; k < 4; ++k) mrow[tid + 256 * k] = Mrow[tid + 256 * k];
    __syncthreads();

    // gather raw energies once into registers
    float g[32];
#pragma unroll
    for (int it = 0; it < 8; ++it) {
        g[4 * it + 0] = mrow[h[it].x];
        g[4 * it + 1] = mrow[h[it].y];
        g[4 * it + 2] = mrow[h[it].z];
        g[4 * it + 3] = mrow[h[it].w];
    }

    // per-thread max + exp-sum (e[] kept for the final store)
    float mloc = g[0];
#pragma unroll
    for (int j = 1; j < 32; ++j) mloc = fmaxf(mloc, g[j]);
    float e[32];
    float s = 0.f;
#pragma unroll
    for (int j = 0; j < 32; ++j) {
        e[j] = __expf(g[j] - mloc);
        s += e[j];
    }

    // fused (m,s) butterfly across the 64-lane wave
    float m = mloc;
#pragma unroll
    for (int off = 32; off > 0; off >>= 1) {
        float om = __shfl_xor(m, off, 64);
        float os = __shfl_xor(s, off, 64);
        float nm_ = fmaxf(m, om);
        s = s * __expf(m - nm_) + os * __expf(om - nm_);
        m = nm_;
    }

    // cross-wave merge via LDS (4 partial pairs)
    const int wave = tid >> 6, lane = tid & 63;
    if (lane == 0) { redm[wave] = m; reds[wave] = s; }
    __syncthreads();
    float M0 = redm[0], S0 = reds[0];
#pragma unroll
    for (int w = 1; w < 4; ++w) {
        float mw = redm[w], sw = reds[w];
        float nm_ = fmaxf(M0, mw);
        S0 = S0 * __expf(M0 - nm_) + sw * __expf(mw - nm_);
        M0 = nm_;
    }

    // single per-thread scale folds max-correction and normalization
    const float scale = __expf(mloc - M0) / S0;

    // coalesced float4 stores straight from registers
    f32x4* out4 = (f32x4*)(out + (size_t)row * SEQ);
#pragma unroll
    for (int it = 0; it < 8; ++it) {
        f32x4 o;
        o.x = e[4 * it + 0] * scale;
        o.y = e[4 * it + 1] * scale;
        o.z = e[4 * it + 2] * scale;
        o.w = e[4 * it + 3] * scale;
        out4[it * 256 + tid] = o;
    }
}

extern "C" void kernel_launch(void* const* d_in, const int* in_sizes, int n_in,
                              void* d_out, int out_size, void* d_ws, size_t ws_size,
                              hipStream_t stream) {
    const int*   his = (const int*)d_in[0];    // (8192,) int32 in [0,1024)
    const int*   cur = (const int*)d_in[1];    // (4096,) int32 in [0,1024)
    const float* M   = (const float*)d_in[2];  // (1024,1024) fp32
    float* out = (float*)d_out;                // (4096,8192) fp32
    (void)d_ws; (void)ws_size;

    fused_kernel<<<NROWS, 256, 0, stream>>>(his, cur, M, out);
}